// Round 13
// baseline (22.319 us; speedup 1.0000x reference)
//
#include <hip/hip_runtime.h>
#include <math.h>

#define HWp 65536   // 256*256

typedef float v2f __attribute__((ext_vector_type(2)));
typedef float v4f __attribute__((ext_vector_type(4)));

__device__ __forceinline__ v2f fma2(v2f a, v2f b, v2f c) {
    return __builtin_elementwise_fma(a, b, c);   // v_pk_fma_f32
}
__device__ __forceinline__ void stream_st2(float* p, v2f v) {
    __builtin_nontemporal_store(v, (v2f*)p);     // 8B nt store
}
__device__ __forceinline__ void stream_st4(float* p, v4f v) {
    __builtin_nontemporal_store(v, (v4f*)p);     // 16B nt store
}
__device__ __forceinline__ float vget(v2f v, int px) { return px ? v.y : v.x; }

// tile row for S plane (i,j): unique entries enumerated col n=min, row r=max
__host__ __device__ constexpr int TRW(int p) {
    const int i = p / 6, j = p % 6;
    const int n = (i < j) ? i : j;
    const int r = (i < j) ? j : i;
    return 6*n - (n*(n-1))/2 + (r - n);
}

__global__ __launch_bounds__(256)
void gp_encoder_kernel(const float* __restrict__ x,
                       const float* __restrict__ Wt,
                       const float* __restrict__ be,
                       float* __restrict__ out)
{
    // B -> A exchange (pixel-pair payloads), indexed [entry][half*64+lane]
    __shared__ v2f Dsh[6][128];
    __shared__ v2f Msh[6][128];
    __shared__ v2f Xsh[3][128];
    // S store-transpose tile: 21 unique entries x 256 px (+4 pad)
    __shared__ float Stile[21][260];

    const int tid  = threadIdx.x;
    const int lane = tid & 63;
    const int wid  = tid >> 6;        // 0,1 = A halves; 2,3 = B halves
    const bool isA = wid < 2;
    const int  half = wid & 1;        // which 128-px half of the row

    // one block = TWO consecutive image rows, processed serially
    const int blk = blockIdx.x;       // 512 blocks
    const int b   = blk >> 7;         // image (128 blocks per image)
    const int rp  = blk & 127;        // row-pair index

    const int  ph = half << 7;        // 0 or 128
    const int  c0 = ph + 2 * lane;    // row-local column of pixel0
    const bool wlo_ok = (c0 != 0);
    const bool whi_ok = (c0 != 254);
    const int  idx_l  = wlo_ok ? c0 - 1 : c0;
    const int  idx_r  = whi_ok ? c0 + 2 : c0;
    const int  xi     = (half << 6) + lane;   // exchange index

    for (int rr = 0; rr < 2; ++rr) {
        const int h    = rp * 2 + rr;
        const int pixb = h << 8;

        // ---------------- taps for BOTH pixels: 27 v2f ----------------
        v2f tp[27];
        #pragma unroll
        for (int ci = 0; ci < 3; ++ci) {
            #pragma unroll
            for (int kh = 0; kh < 3; ++kh) {
                const int hh = h + kh - 1;     // scalar
                float lv = 0.f, rv = 0.f;
                v2f   mv = (v2f){0.f, 0.f};
                if ((unsigned)hh < 256u) {     // uniform branch
                    const float* rp_ = x + (b*3 + ci) * HWp + hh * 256;
                    mv = *reinterpret_cast<const v2f*>(rp_ + c0);
                    lv = rp_[idx_l];
                    rv = rp_[idx_r];
                    lv = wlo_ok ? lv : 0.f;
                    rv = whi_ok ? rv : 0.f;
                }
                tp[ci*9 + kh*3 + 0] = (v2f){lv, mv.x};
                tp[ci*9 + kh*3 + 1] = mv;
                tp[ci*9 + kh*3 + 2] = (v2f){mv.y, rv};
            }
        }

        auto conv_ch = [&](int ch) -> v2f {
            const float bb = be[ch];
            v2f acc = (v2f){bb, bb};
            const float* wp = Wt + ch * 27;
            #pragma unroll
            for (int t = 0; t < 27; ++t) {
                const float wt = wp[t];
                acc = fma2(tp[t], (v2f){wt, wt}, acc);
            }
            return acc;
        };

        // scalar output-plane bases (row origin)
        float* out_xf = out                      + b*3*HWp  + pixb;
        float* out_m  = out + 4*3*HWp            + b*6*HWp  + pixb;
        float* out_S  = out + (4*3+4*6)*HWp      + b*36*HWp + pixb;
        float* out_y  = out + (4*3+4*6+4*36)*HWp + b*3*HWp  + pixb;

        if (!isA) {
            // ======== wave B: conv(m/s/xf) -> store m,xf -> publish d,m,xf ========
            v2f pbm[6], pbs[6], pxf[3];
            #pragma unroll
            for (int o = 0; o < 6; ++o) pbm[o] = conv_ch(o);
            #pragma unroll
            for (int o = 0; o < 6; ++o) pbs[o] = conv_ch(6 + o);
            #pragma unroll
            for (int o = 0; o < 3; ++o) pxf[o] = conv_ch(27 + o);

            #pragma unroll
            for (int c = 0; c < 6; ++c) {
                stream_st2(&out_m[c*HWp + c0], pbm[c]);
                Msh[c][xi] = pbm[c];
            }
            #pragma unroll
            for (int i = 0; i < 3; ++i) {
                stream_st2(&out_xf[i*HWp + c0], pxf[i]);
                Xsh[i][xi] = pxf[i];
            }
            #pragma unroll
            for (int k = 0; k < 6; ++k) {
                const v2f s = pbs[k];
                Dsh[k][xi] = __builtin_elementwise_max(s * s, (v2f){1e-6f, 1e-6f});
            }

            __syncthreads();   // bar1: release A
            __syncthreads();   // bar2: A's Stile writes done
            continue;
        }

        // ======== wave A: conv(angle) -> trig -> Givens -> S -> stores -> tail ========
        v2f pa[15];
        #pragma unroll
        for (int o = 0; o < 15; ++o)
            pa[o] = conv_ch(12 + o);

        // sigmoid + sin/cos of 2*pi*sg (HW trig takes revolutions)
        v2f cs[15], ss[15];
        #pragma unroll
        for (int k = 0; k < 15; ++k) {
            const float e0 = __expf(-pa[k].x);
            const float e1 = __expf(-pa[k].y);
            const float g0 = __builtin_amdgcn_rcpf(1.f + e0);
            const float g1 = __builtin_amdgcn_rcpf(1.f + e1);
            cs[k] = (v2f){__builtin_amdgcn_cosf(g0), __builtin_amdgcn_cosf(g1)};
            ss[k] = (v2f){__builtin_amdgcn_sinf(g0), __builtin_amdgcn_sinf(g1)};
        }

        v2f R[6][6];
        #pragma unroll
        for (int r = 0; r < 6; ++r)
            #pragma unroll
            for (int c = 0; c < 6; ++c)
                R[r][c] = (r == c) ? (v2f){1.f, 1.f} : (v2f){0.f, 0.f};

        const int PI_[15] = {0,0,0,0,0,1,1,1,1,2,2,2,3,3,4};
        const int PJ_[15] = {1,2,3,4,5,2,3,4,5,3,4,5,4,5,5};
        #pragma unroll
        for (int k = 0; k < 15; ++k) {
            const int i = PI_[k], j = PJ_[k];
            const v2f c2 = cs[k], s2 = ss[k];
            #pragma unroll
            for (int r = 0; r < 6; ++r) {
                const v2f ri = R[r][i], rj = R[r][j];
                R[r][i] = fma2(c2, ri, s2 * rj);
                R[r][j] = fma2(c2, rj, -(s2 * ri));
            }
        }

        __syncthreads();   // bar1: d, m, xf ready

        v2f dk[6], mm[6], xx[3];
        #pragma unroll
        for (int k = 0; k < 6; ++k) dk[k] = Dsh[k][xi];
        #pragma unroll
        for (int k = 0; k < 6; ++k) mm[k] = Msh[k][xi];
        #pragma unroll
        for (int k = 0; k < 3; ++k) xx[k] = Xsh[k][xi];

        // S = R diag(d) R^T: 21 unique entries -> Stile; keep syx/syy for tail
        v2f syx2[3][3], syy2[3][3];
        #pragma unroll
        for (int n = 0; n < 6; ++n) {
            v2f t[6];
            #pragma unroll
            for (int k = 0; k < 6; ++k)
                t[k] = dk[k] * R[n][k];
            #pragma unroll
            for (int r = n; r < 6; ++r) {
                v2f acc = t[0] * R[r][0];
                #pragma unroll
                for (int k = 1; k < 6; ++k)
                    acc = fma2(t[k], R[r][k], acc);
                *reinterpret_cast<v2f*>(&Stile[TRW(r*6 + n)][c0]) = acc;
                if (r >= 3 && n < 3)  syx2[r-3][n] = acc;
                if (r >= 3 && n >= 3) { syy2[r-3][n-3] = acc;
                                        if (r != n) syy2[n-3][r-3] = acc; }
            }
        }

        __syncthreads();   // bar2: both A halves done writing Stile

        // cooperative plane stores: 36 planes x 1KB full-row nt dwordx4 (18/half)
        #define STP(p) { v4f v = *reinterpret_cast<const v4f*>(&Stile[TRW(p)][4*lane]); \
                         stream_st4(&out_S[(p)*HWp + 4*lane], v); }
        if (half == 0) {
            STP(0)  STP(2)  STP(4)  STP(6)  STP(8)  STP(10)
            STP(12) STP(14) STP(16) STP(18) STP(20) STP(22)
            STP(24) STP(26) STP(28) STP(30) STP(32) STP(34)
        } else {
            STP(1)  STP(3)  STP(5)  STP(7)  STP(9)  STP(11)
            STP(13) STP(15) STP(17) STP(19) STP(21) STP(23)
            STP(25) STP(27) STP(29) STP(31) STP(33) STP(35)
        }
        #undef STP

        // f64 tail: Q = -S_yy^{-1} S_yx (exact identity), y = my - Qp(xf - mx)
        float yv[2][3];
        #pragma unroll
        for (int px = 0; px < 2; ++px) {
            const double a00 = (double)vget(syy2[0][0], px), a01 = (double)vget(syy2[0][1], px), a02 = (double)vget(syy2[0][2], px);
            const double a10 = (double)vget(syy2[1][0], px), a11 = (double)vget(syy2[1][1], px), a12 = (double)vget(syy2[1][2], px);
            const double a20 = (double)vget(syy2[2][0], px), a21 = (double)vget(syy2[2][1], px), a22 = (double)vget(syy2[2][2], px);

            const double det = a00*(a11*a22 - a12*a21)
                             - a01*(a10*a22 - a12*a20)
                             + a02*(a10*a21 - a11*a20);
            const double idet = 1.0 / det;

            double inv[3][3];
            inv[0][0] =  (a11*a22 - a12*a21) * idet;
            inv[0][1] = -(a01*a22 - a02*a21) * idet;
            inv[0][2] =  (a01*a12 - a02*a11) * idet;
            inv[1][0] = -(a10*a22 - a12*a20) * idet;
            inv[1][1] =  (a00*a22 - a02*a20) * idet;
            inv[1][2] = -(a00*a12 - a02*a10) * idet;
            inv[2][0] =  (a10*a21 - a11*a20) * idet;
            inv[2][1] = -(a00*a21 - a01*a20) * idet;
            inv[2][2] =  (a00*a11 - a01*a10) * idet;

            double Qp[3][3];
            #pragma unroll
            for (int r = 0; r < 3; ++r)
                #pragma unroll
                for (int c = 0; c < 3; ++c) {
                    double acc = 0.0;
                    #pragma unroll
                    for (int k = 0; k < 3; ++k)
                        acc = fma(inv[r][k], (double)vget(syx2[k][c], px), acc);
                    Qp[r][c] = acc;
                }

            #pragma unroll
            for (int i = 0; i < 3; ++i) {
                double acc = (double)vget(mm[3 + i], px);
                #pragma unroll
                for (int n = 0; n < 3; ++n)
                    acc = fma(-Qp[i][n], (double)vget(xx[n], px) - (double)vget(mm[n], px), acc);
                yv[px][i] = (float)acc;
            }
        }

        #pragma unroll
        for (int i = 0; i < 3; ++i)
            stream_st2(&out_y[i*HWp + c0], (v2f){yv[0][i], yv[1][i]});
    }
}

extern "C" void kernel_launch(void* const* d_in, const int* in_sizes, int n_in,
                              void* d_out, int out_size, void* d_ws, size_t ws_size,
                              hipStream_t stream) {
    const float* x  = (const float*)d_in[0];
    const float* Wt = (const float*)d_in[1];
    const float* be = (const float*)d_in[2];
    float* out = (float*)d_out;

    dim3 grid(512);    // 4 images x 128 row-pairs; two rows per block, serial
    dim3 block(256);   // A0,A1 (R/S/tail) + B0,B1 (conv m/s/xf)
    hipLaunchKernelGGL(gp_encoder_kernel, grid, block, 0, stream, x, Wt, be, out);
}

// Round 15
// 19.359 us; speedup vs baseline: 1.1529x; 1.1529x over previous
//
#include <hip/hip_runtime.h>
#include <math.h>

#define HWp 65536   // 256*256

typedef float v2f __attribute__((ext_vector_type(2)));

__device__ __forceinline__ v2f fma2(v2f a, v2f b, v2f c) {
    return __builtin_elementwise_fma(a, b, c);   // v_pk_fma_f32
}
__device__ __forceinline__ void stream_st2(float* p, v2f v) {
    __builtin_nontemporal_store(v, (v2f*)p);     // 8B nt store
}
__device__ __forceinline__ float vget(v2f v, int px) { return px ? v.y : v.x; }

// tile row for S plane (i,j): unique entries enumerated col n=min, row r=max
__host__ __device__ constexpr int TRW(int p) {
    const int i = p / 6, j = p % 6;
    const int n = (i < j) ? i : j;
    const int r = (i < j) ? j : i;
    return 6*n - (n*(n-1))/2 + (r - n);
}

__global__ __launch_bounds__(128)
void gp_encoder_kernel(const float* __restrict__ x,
                       const float* __restrict__ Wt,
                       const float* __restrict__ be,
                       float* __restrict__ out)
{
    // B -> A exchange (pixel-pair payloads): [entry][lane]
    __shared__ v2f Dsh[6][64];
    __shared__ v2f Msh[6][64];
    __shared__ v2f Xsh[3][64];
    // S store-transpose tile: 21 unique entries x 128 px (+2 pad, 8B-aligned rows)
    __shared__ float Stile[21][130];   // total LDS ~18.6 KB -> 8 blocks/CU resident

    const int lane = threadIdx.x & 63;
    const int wid  = threadIdx.x >> 6;   // 0 = wave A (R/S/tail), 1 = wave B (conv m/s/xf + S stores)

    // block = one 128-px half-row: 4 images x 256 rows x 2 halves = 2048 blocks
    const int blk  = blockIdx.x;
    const int b    = blk >> 9;           // image (512 blocks per image)
    const int idx  = blk & 511;
    const int h    = idx >> 1;           // row 0..255
    const int half = idx & 1;
    const int w0   = half << 7;          // 0 or 128
    const int pixb = h << 8;

    const int  lc = 2 * lane;            // block-local column of pixel0
    const int  c0 = w0 + lc;             // absolute column
    const bool wlo_ok = (c0 != 0);       // true image edges only
    const bool whi_ok = (c0 != 254);
    const int  idx_l  = wlo_ok ? c0 - 1 : c0;
    const int  idx_r  = whi_ok ? c0 + 2 : c0;

    // ---------------- taps for BOTH pixels: 27 v2f ----------------
    v2f tp[27];
    #pragma unroll
    for (int ci = 0; ci < 3; ++ci) {
        #pragma unroll
        for (int kh = 0; kh < 3; ++kh) {
            const int hh = h + kh - 1;     // scalar
            float lv = 0.f, rv = 0.f;
            v2f   mv = (v2f){0.f, 0.f};
            if ((unsigned)hh < 256u) {     // uniform branch
                const float* rp = x + (b*3 + ci) * HWp + hh * 256;
                mv = *reinterpret_cast<const v2f*>(rp + c0);
                lv = rp[idx_l];
                rv = rp[idx_r];
                lv = wlo_ok ? lv : 0.f;
                rv = whi_ok ? rv : 0.f;
            }
            tp[ci*9 + kh*3 + 0] = (v2f){lv, mv.x};
            tp[ci*9 + kh*3 + 1] = mv;
            tp[ci*9 + kh*3 + 2] = (v2f){mv.y, rv};
        }
    }

    auto conv_ch = [&](int ch) -> v2f {
        const float bb = be[ch];
        v2f acc = (v2f){bb, bb};
        const float* wp = Wt + ch * 27;
        #pragma unroll
        for (int t = 0; t < 27; ++t) {
            const float wt = wp[t];
            acc = fma2(tp[t], (v2f){wt, wt}, acc);
        }
        return acc;
    };

    // scalar output-plane bases (row origin; store column = c0)
    float* out_xf = out                      + b*3*HWp  + pixb;
    float* out_m  = out + 4*3*HWp            + b*6*HWp  + pixb;
    float* out_S  = out + (4*3+4*6)*HWp      + b*36*HWp + pixb;
    float* out_y  = out + (4*3+4*6+4*36)*HWp + b*3*HWp  + pixb;

    if (wid == 1) {
        // ======== wave B: conv(m/s/xf) -> store m,xf -> publish d,m,xf -> S stores ========
        v2f pbm[6], pbs[6], pxf[3];
        #pragma unroll
        for (int o = 0; o < 6; ++o) pbm[o] = conv_ch(o);
        #pragma unroll
        for (int o = 0; o < 6; ++o) pbs[o] = conv_ch(6 + o);
        #pragma unroll
        for (int o = 0; o < 3; ++o) pxf[o] = conv_ch(27 + o);

        #pragma unroll
        for (int c = 0; c < 6; ++c) {
            stream_st2(&out_m[c*HWp + c0], pbm[c]);
            Msh[c][lane] = pbm[c];
        }
        #pragma unroll
        for (int i = 0; i < 3; ++i) {
            stream_st2(&out_xf[i*HWp + c0], pxf[i]);
            Xsh[i][lane] = pxf[i];
        }
        #pragma unroll
        for (int k = 0; k < 6; ++k) {
            const v2f s = pbs[k];
            Dsh[k][lane] = __builtin_elementwise_max(s * s, (v2f){1e-6f, 1e-6f});
        }

        __syncthreads();   // bar1: release A
        __syncthreads();   // bar2: A's Stile writes complete

        // cooperative S-plane stores (overlaps A's f64 tail)
        #pragma unroll
        for (int p = 0; p < 36; ++p) {
            const v2f v = *reinterpret_cast<const v2f*>(&Stile[TRW(p)][lc]);
            stream_st2(&out_S[p*HWp + c0], v);
        }
        return;
    }

    // ======== wave A: conv(angle) -> trig -> Givens -> (bar1) -> S -> (bar2) -> tail ========
    v2f pa[15];
    #pragma unroll
    for (int o = 0; o < 15; ++o)
        pa[o] = conv_ch(12 + o);

    // sigmoid + sin/cos of 2*pi*sg (HW trig takes revolutions)
    v2f cs[15], ss[15];
    #pragma unroll
    for (int k = 0; k < 15; ++k) {
        const float e0 = __expf(-pa[k].x);
        const float e1 = __expf(-pa[k].y);
        const float g0 = __builtin_amdgcn_rcpf(1.f + e0);
        const float g1 = __builtin_amdgcn_rcpf(1.f + e1);
        cs[k] = (v2f){__builtin_amdgcn_cosf(g0), __builtin_amdgcn_cosf(g1)};
        ss[k] = (v2f){__builtin_amdgcn_sinf(g0), __builtin_amdgcn_sinf(g1)};
    }

    v2f R[6][6];
    #pragma unroll
    for (int r = 0; r < 6; ++r)
        #pragma unroll
        for (int c = 0; c < 6; ++c)
            R[r][c] = (r == c) ? (v2f){1.f, 1.f} : (v2f){0.f, 0.f};

    const int PI_[15] = {0,0,0,0,0,1,1,1,1,2,2,2,3,3,4};
    const int PJ_[15] = {1,2,3,4,5,2,3,4,5,3,4,5,4,5,5};
    #pragma unroll
    for (int k = 0; k < 15; ++k) {
        const int i = PI_[k], j = PJ_[k];
        const v2f c2 = cs[k], s2 = ss[k];
        #pragma unroll
        for (int r = 0; r < 6; ++r) {
            const v2f ri = R[r][i], rj = R[r][j];
            R[r][i] = fma2(c2, ri, s2 * rj);
            R[r][j] = fma2(c2, rj, -(s2 * ri));
        }
    }

    __syncthreads();   // bar1: d, m, xf ready

    v2f dk[6], mm[6], xx[3];
    #pragma unroll
    for (int k = 0; k < 6; ++k) dk[k] = Dsh[k][lane];
    #pragma unroll
    for (int k = 0; k < 6; ++k) mm[k] = Msh[k][lane];
    #pragma unroll
    for (int k = 0; k < 3; ++k) xx[k] = Xsh[k][lane];

    // S = R diag(d) R^T: 21 unique entries -> Stile; keep syx/syy for tail
    v2f syx2[3][3], syy2[3][3];
    #pragma unroll
    for (int n = 0; n < 6; ++n) {
        v2f t[6];
        #pragma unroll
        for (int k = 0; k < 6; ++k)
            t[k] = dk[k] * R[n][k];
        #pragma unroll
        for (int r = n; r < 6; ++r) {
            v2f acc = t[0] * R[r][0];
            #pragma unroll
            for (int k = 1; k < 6; ++k)
                acc = fma2(t[k], R[r][k], acc);
            *reinterpret_cast<v2f*>(&Stile[TRW(r*6 + n)][lc]) = acc;
            if (r >= 3 && n < 3)  syx2[r-3][n] = acc;
            if (r >= 3 && n >= 3) { syy2[r-3][n-3] = acc;
                                    if (r != n) syy2[n-3][r-3] = acc; }
        }
    }

    __syncthreads();   // bar2: Stile complete -> B stores S planes

    // f64 tail (runs concurrently with B's S stores):
    // Q = -S_yy^{-1} S_yx (exact identity), y = my - Qp(xf - mx)
    float yv[2][3];
    #pragma unroll
    for (int px = 0; px < 2; ++px) {
        const double a00 = (double)vget(syy2[0][0], px), a01 = (double)vget(syy2[0][1], px), a02 = (double)vget(syy2[0][2], px);
        const double a10 = (double)vget(syy2[1][0], px), a11 = (double)vget(syy2[1][1], px), a12 = (double)vget(syy2[1][2], px);
        const double a20 = (double)vget(syy2[2][0], px), a21 = (double)vget(syy2[2][1], px), a22 = (double)vget(syy2[2][2], px);

        const double det = a00*(a11*a22 - a12*a21)
                         - a01*(a10*a22 - a12*a20)
                         + a02*(a10*a21 - a11*a20);
        const double idet = 1.0 / det;

        double inv[3][3];
        inv[0][0] =  (a11*a22 - a12*a21) * idet;
        inv[0][1] = -(a01*a22 - a02*a21) * idet;
        inv[0][2] =  (a01*a12 - a02*a11) * idet;
        inv[1][0] = -(a10*a22 - a12*a20) * idet;
        inv[1][1] =  (a00*a22 - a02*a20) * idet;
        inv[1][2] = -(a00*a12 - a02*a10) * idet;
        inv[2][0] =  (a10*a21 - a11*a20) * idet;
        inv[2][1] = -(a00*a21 - a01*a20) * idet;
        inv[2][2] =  (a00*a11 - a01*a10) * idet;

        double Qp[3][3];
        #pragma unroll
        for (int r = 0; r < 3; ++r)
            #pragma unroll
            for (int c = 0; c < 3; ++c) {
                double acc = 0.0;
                #pragma unroll
                for (int k = 0; k < 3; ++k)
                    acc = fma(inv[r][k], (double)vget(syx2[k][c], px), acc);
                Qp[r][c] = acc;
            }

        #pragma unroll
        for (int i = 0; i < 3; ++i) {
            double acc = (double)vget(mm[3 + i], px);
            #pragma unroll
            for (int n = 0; n < 3; ++n)
                acc = fma(-Qp[i][n], (double)vget(xx[n], px) - (double)vget(mm[n], px), acc);
            yv[px][i] = (float)acc;
        }
    }

    #pragma unroll
    for (int i = 0; i < 3; ++i)
        stream_st2(&out_y[i*HWp + c0], (v2f){yv[0][i], yv[1][i]});
}

extern "C" void kernel_launch(void* const* d_in, const int* in_sizes, int n_in,
                              void* d_out, int out_size, void* d_ws, size_t ws_size,
                              hipStream_t stream) {
    const float* x  = (const float*)d_in[0];
    const float* Wt = (const float*)d_in[1];
    const float* be = (const float*)d_in[2];
    float* out = (float*)d_out;

    dim3 grid(2048);   // 4 images x 256 rows x 2 half-rows (128 px per block)
    dim3 block(128);   // wave A (R/S/tail) + wave B (conv m/s/xf + S stores)
    hipLaunchKernelGGL(gp_encoder_kernel, grid, block, 0, stream, x, Wt, be, out);
}